// Round 1
// baseline (841.707 us; speedup 1.0000x reference)
//
#include <hip/hip_runtime.h>
#include <math.h>

// Problem constants (from reference): D=64 dialogues, L=64, DIM=512, G=256
// m = 3*L = 192 nodes/hyperedges per dialogue, k = 12, N = D*L = 4096
#define NDIAL 64
#define LUTT  64
#define M3    192
#define DIMF  512
#define GDIM  256
#define NROW  4096
#define TOPK  12
#define INV_TAU (1.0f/0.07f)

// ---------------------------------------------------------------------------
// Generic fp32 64x64 tile GEMM helper. 256 threads, each computes 4x4.
// TA: A element (m,k) at A[k*lda+m] (transposed source)
// TB: B element (k,n) at B[n*ldb+k] (transposed source, i.e. B rows are "n")
// SA/SB: scale A rows / B cols by sa[m] / sb[n] while staging.
// ---------------------------------------------------------------------------
template<int KDIM, bool TA, bool TB, bool SA, bool SB>
__device__ __forceinline__ void mm64(
    const float* __restrict__ A, int lda, const float* __restrict__ sa,
    const float* __restrict__ B, int ldb, const float* __restrict__ sb,
    float acc[4][4])
{
    __shared__ float As[64][33];   // padded: compute reads column kk over rows
    __shared__ float Bs[32][68];   // padded to keep float4 alignment (68%4==0)
    const int tid = threadIdx.x;
    const int tx = tid & 15, ty = tid >> 4;

#pragma unroll
    for (int r = 0; r < 4; r++)
#pragma unroll
        for (int c = 0; c < 4; c++) acc[r][c] = 0.f;

    for (int k0 = 0; k0 < KDIM; k0 += 32) {
        // ---- stage A tile (64 rows x 32 k) ----
        if (!TA) {
#pragma unroll
            for (int i = 0; i < 2; i++) {
                int f = tid + i * 256;           // 0..511 float4s
                int m = f >> 3, k4 = f & 7;
                const float4 v4 = *(const float4*)(A + (size_t)m * lda + k0 + k4 * 4);
                float s = SA ? sa[m] : 1.f;
                As[m][k4 * 4 + 0] = v4.x * s;
                As[m][k4 * 4 + 1] = v4.y * s;
                As[m][k4 * 4 + 2] = v4.z * s;
                As[m][k4 * 4 + 3] = v4.w * s;
            }
        } else {
#pragma unroll
            for (int i = 0; i < 2; i++) {
                int f = tid + i * 256;
                int k = f >> 4, m4 = f & 15;
                const float4 v4 = *(const float4*)(A + (size_t)(k0 + k) * lda + m4 * 4);
                As[m4 * 4 + 0][k] = v4.x;
                As[m4 * 4 + 1][k] = v4.y;
                As[m4 * 4 + 2][k] = v4.z;
                As[m4 * 4 + 3][k] = v4.w;
            }
        }
        // ---- stage B tile (32 k x 64 cols) ----
        if (!TB) {
#pragma unroll
            for (int i = 0; i < 2; i++) {
                int f = tid + i * 256;
                int k = f >> 4, n4 = f & 15;
                float4 v4 = *(const float4*)(B + (size_t)(k0 + k) * ldb + n4 * 4);
                *(float4*)&Bs[k][n4 * 4] = v4;
            }
        } else {
#pragma unroll
            for (int i = 0; i < 2; i++) {
                int f = tid + i * 256;
                int n = f >> 3, k4 = f & 7;
                const float4 v4 = *(const float4*)(B + (size_t)n * ldb + k0 + k4 * 4);
                float s = SB ? sb[n] : 1.f;
                Bs[k4 * 4 + 0][n] = v4.x * s;
                Bs[k4 * 4 + 1][n] = v4.y * s;
                Bs[k4 * 4 + 2][n] = v4.z * s;
                Bs[k4 * 4 + 3][n] = v4.w * s;
            }
        }
        __syncthreads();
#pragma unroll
        for (int kk = 0; kk < 32; kk++) {
            float4 b = *(const float4*)&Bs[kk][tx * 4];
#pragma unroll
            for (int r = 0; r < 4; r++) {
                float av = As[ty * 4 + r][kk];
                acc[r][0] += av * b.x;
                acc[r][1] += av * b.y;
                acc[r][2] += av * b.z;
                acc[r][3] += av * b.w;
            }
        }
        __syncthreads();
    }
}

// node j of dialogue d -> source row pointer
__device__ __forceinline__ const float* node_ptr(const float* t, const float* a,
                                                 const float* v, int d, int j) {
    int mod = j >> 6, i = j & 63;
    const float* base = (mod == 0) ? t : (mod == 1) ? a : v;
    return base + (size_t)(d * 64 + i) * DIMF;
}

// ---- K0: per-node squared norms (wave per row) ----
__global__ void k0_sq(const float* __restrict__ t, const float* __restrict__ a,
                      const float* __restrict__ v, float* __restrict__ sq) {
    int lane = threadIdx.x & 63, wv = threadIdx.x >> 6;
    int n = blockIdx.x * 4 + wv;                 // 0..12287
    int d = n / M3, j = n % M3;
    const float4* s4 = (const float4*)node_ptr(t, a, v, d, j);
    float s = 0.f;
#pragma unroll
    for (int q = 0; q < 2; q++) {
        float4 x = s4[lane + q * 64];
        s += x.x * x.x + x.y * x.y + x.z * x.z + x.w * x.w;
    }
    for (int o = 32; o; o >>= 1) s += __shfl_down(s, o);
    if (lane == 0) sq[n] = s;
}

// ---- K1: clamped squared distances per dialogue (Gram tiles) ----
__global__ void k1_d2(const float* __restrict__ t, const float* __restrict__ a,
                      const float* __restrict__ v, const float* __restrict__ sq,
                      float* __restrict__ d2) {
    int tileid = blockIdx.x;             // 0..8
    int d = blockIdx.y;
    int bi = tileid / 3, bj = tileid % 3;
    const float* A = ((bi == 0) ? t : (bi == 1) ? a : v) + (size_t)d * 64 * DIMF;
    const float* B = ((bj == 0) ? t : (bj == 1) ? a : v) + (size_t)d * 64 * DIMF;
    float acc[4][4];
    mm64<DIMF, false, true, false, false>(A, DIMF, nullptr, B, DIMF, nullptr, acc);
    int tx = threadIdx.x & 15, ty = threadIdx.x >> 4;
    const float* sqd = sq + d * M3;
    float* outp = d2 + (size_t)d * M3 * M3;
#pragma unroll
    for (int r = 0; r < 4; r++)
#pragma unroll
        for (int c = 0; c < 4; c++) {
            int il = bi * 64 + ty * 4 + r;
            int jl = bj * 64 + tx * 4 + c;
            float vv = sqd[il] + sqd[jl] - 2.f * acc[r][c];
            outp[(size_t)il * M3 + jl] = fmaxf(vv, 0.f);
        }
}

// ---- K2: top-12 smallest per row (stable: lower index wins ties) + build H ----
__global__ void k2_topk(const float* __restrict__ d2, float* __restrict__ H) {
    int r = blockIdx.x * 256 + threadIdx.x;      // 0..12287
    int d = r / M3, e = r % M3;
    const float* row = d2 + ((size_t)d * M3 + e) * M3;
    float bd[TOPK];
    int bx[TOPK];
#pragma unroll
    for (int i = 0; i < TOPK; i++) { bd[i] = 3.4e38f; bx[i] = -1; }
    for (int n = 0; n < M3; n++) {
        float vv = row[n];
        if (vv < bd[TOPK - 1]) {
            int p = TOPK - 1;
            while (p > 0 && bd[p - 1] > vv) {
                bd[p] = bd[p - 1]; bx[p] = bx[p - 1]; p--;
            }
            bd[p] = vv; bx[p] = n;
        }
    }
    float* Hrow = H + ((size_t)d * M3 + e) * M3;
    for (int n = 0; n < M3; n++) Hrow[n] = 0.f;
#pragma unroll
    for (int i = 0; i < TOPK; i++) Hrow[bx[i]] = 1.f;
    int u = e / 3;
    Hrow[u] = 1.f; Hrow[u + 64] = 1.f; Hrow[u + 128] = 1.f;
}

// ---- Kdeg: row sums (deg_e) and column sums (deg_v) of H ----
__global__ void k_deg(const float* __restrict__ H, float* __restrict__ degE,
                      float* __restrict__ degV) {
    int tid = blockIdx.x * 256 + threadIdx.x;
    if (tid < 12288) {
        int d = tid / M3, e = tid % M3;
        const float* row = H + ((size_t)d * M3 + e) * M3;
        float s = 0.f;
        for (int n = 0; n < M3; n++) s += row[n];
        degE[tid] = s;
    } else if (tid < 24576) {
        int q = tid - 12288;
        int d = q / M3, n = q % M3;
        const float* col = H + (size_t)d * M3 * M3 + n;
        float s = 0.f;
        for (int e = 0; e < M3; e++) s += col[(size_t)e * M3];
        degV[q] = s;
    }
}

// ---- K3: X = feat @ W_fc + b_fc ----
__global__ void k3_x(const float* __restrict__ t, const float* __restrict__ a,
                     const float* __restrict__ v, const float* __restrict__ Wfc,
                     const float* __restrict__ bfc, float* __restrict__ X) {
    int cb = blockIdx.x, rt = blockIdx.y;
    int d = rt / 3, mod = rt % 3;
    const float* A = ((mod == 0) ? t : (mod == 1) ? a : v) + (size_t)d * 64 * DIMF;
    const float* B = Wfc + cb * 64;
    float acc[4][4];
    mm64<DIMF, false, false, false, false>(A, DIMF, nullptr, B, GDIM, nullptr, acc);
    int tx = threadIdx.x & 15, ty = threadIdx.x >> 4;
#pragma unroll
    for (int r = 0; r < 4; r++)
#pragma unroll
        for (int c = 0; c < 4; c++) {
            int i = ty * 4 + r;
            int col = cb * 64 + tx * 4 + c;
            X[((size_t)d * M3 + mod * 64 + i) * GDIM + col] = acc[r][c] + bfc[col];
        }
}

// ---- K4: E = (H @ X) / deg_e ----
__global__ void k4_E(const float* __restrict__ H, const float* __restrict__ X,
                     const float* __restrict__ degE, float* __restrict__ E) {
    int cb = blockIdx.x, bi = blockIdx.y, d = blockIdx.z;
    const float* A = H + (size_t)d * M3 * M3 + (size_t)(bi * 64) * M3;
    const float* B = X + (size_t)d * M3 * GDIM + cb * 64;
    float acc[4][4];
    mm64<M3, false, false, false, false>(A, M3, nullptr, B, GDIM, nullptr, acc);
    int tx = threadIdx.x & 15, ty = threadIdx.x >> 4;
#pragma unroll
    for (int r = 0; r < 4; r++) {
        int e = bi * 64 + ty * 4 + r;
        float dg = degE[d * M3 + e];
#pragma unroll
        for (int c = 0; c < 4; c++) {
            int col = cb * 64 + tx * 4 + c;
            E[((size_t)d * M3 + e) * GDIM + col] = acc[r][c] / dg;
        }
    }
}

// ---- K5: Y = (H^T @ E) / deg_v ----
__global__ void k5_Y(const float* __restrict__ H, const float* __restrict__ E,
                     const float* __restrict__ degV, float* __restrict__ Y) {
    int cb = blockIdx.x, bi = blockIdx.y, d = blockIdx.z;
    const float* A = H + (size_t)d * M3 * M3 + bi * 64;   // (m,k) = A[k*lda+m]
    const float* B = E + (size_t)d * M3 * GDIM + cb * 64;
    float acc[4][4];
    mm64<M3, true, false, false, false>(A, M3, nullptr, B, GDIM, nullptr, acc);
    int tx = threadIdx.x & 15, ty = threadIdx.x >> 4;
#pragma unroll
    for (int r = 0; r < 4; r++) {
        int n = bi * 64 + ty * 4 + r;
        float dg = degV[d * M3 + n];
#pragma unroll
        for (int c = 0; c < 4; c++) {
            int col = cb * 64 + tx * 4 + c;
            Y[((size_t)d * M3 + n) * GDIM + col] = acc[r][c] / dg;
        }
    }
}

// ---- K6: out = relu(Y @ W_h + b_h), scattered into d_out as [tn an vn] ----
__global__ void k6_out(const float* __restrict__ Y, const float* __restrict__ Wh,
                       const float* __restrict__ bh, float* __restrict__ outp) {
    int cb = blockIdx.x, rt = blockIdx.y;
    int d = rt / 3, mod = rt % 3;
    const float* A = Y + ((size_t)d * M3 + mod * 64) * GDIM;
    const float* B = Wh + cb * 64;
    float acc[4][4];
    mm64<GDIM, false, false, false, false>(A, GDIM, nullptr, B, GDIM, nullptr, acc);
    int tx = threadIdx.x & 15, ty = threadIdx.x >> 4;
#pragma unroll
    for (int r = 0; r < 4; r++)
#pragma unroll
        for (int c = 0; c < 4; c++) {
            int i = ty * 4 + r;
            int col = cb * 64 + tx * 4 + c;
            float vv = acc[r][c] + bh[col];
            outp[(size_t)(d * 64 + i) * 768 + mod * GDIM + col] = fmaxf(vv, 0.f);
        }
}

// ---- K7: inverse norms of tn/an/vn rows (wave per row) ----
__global__ void k7_norm(const float* __restrict__ outp, float* __restrict__ inv) {
    int lane = threadIdx.x & 63, wv = threadIdx.x >> 6;
    int idx = blockIdx.x * 4 + wv;               // 0..12287
    int p = idx / NROW, r = idx % NROW;
    const float4* src = (const float4*)(outp + (size_t)r * 768 + p * GDIM);
    float4 x = src[lane];
    float s = x.x * x.x + x.y * x.y + x.z * x.z + x.w * x.w;
    for (int o = 32; o; o >>= 1) s += __shfl_down(s, o);
    if (lane == 0) inv[idx] = 1.f / (sqrtf(s) + 1e-8f);
}

// ---- K8: zero the row/col exp-sum accumulators ----
__global__ void k8_zero(float* __restrict__ rs, float* __restrict__ cs) {
    int i = blockIdx.x * 256 + threadIdx.x;
    if (i < 3 * NROW) { rs[i] = 0.f; cs[i] = 0.f; }
}

// ---- K9: sim tiles; accumulate exp row/col sums + diagonal sims ----
// No max-subtraction needed: |sim| <= 1/tau = 14.29 -> exp in fp32 range.
__global__ void k9_sim(const float* __restrict__ outp, const float* __restrict__ inv,
                       float* __restrict__ rs, float* __restrict__ cs,
                       float* __restrict__ diag) {
    int cj = blockIdx.x, ci = blockIdx.y, p = blockIdx.z;
    int px = (p == 2) ? 1 : 0;
    int py = (p == 0) ? 1 : 2;
    const float* A = outp + (size_t)(ci * 64) * 768 + px * GDIM;
    const float* B = outp + (size_t)(cj * 64) * 768 + py * GDIM;
    const float* sa = inv + px * NROW + ci * 64;
    const float* sb = inv + py * NROW + cj * 64;
    float acc[4][4];
    mm64<GDIM, false, true, true, true>(A, 768, sa, B, 768, sb, acc);

    __shared__ float rsum[64], csum[64];
    int tx = threadIdx.x & 15, ty = threadIdx.x >> 4;
    if (threadIdx.x < 64) { rsum[threadIdx.x] = 0.f; csum[threadIdx.x] = 0.f; }
    __syncthreads();

    float rpart[4] = {0, 0, 0, 0}, cpart[4] = {0, 0, 0, 0};
#pragma unroll
    for (int r = 0; r < 4; r++)
#pragma unroll
        for (int c = 0; c < 4; c++) {
            float s = acc[r][c] * INV_TAU;
            float e = __expf(s);
            rpart[r] += e;
            cpart[c] += e;
            if (ci == cj && (ty * 4 + r) == (tx * 4 + c))
                diag[p * NROW + ci * 64 + ty * 4 + r] = s;
        }
#pragma unroll
    for (int r = 0; r < 4; r++) atomicAdd(&rsum[ty * 4 + r], rpart[r]);
#pragma unroll
    for (int c = 0; c < 4; c++) atomicAdd(&csum[tx * 4 + c], cpart[c]);
    __syncthreads();
    if (threadIdx.x < 64)
        atomicAdd(&rs[p * NROW + ci * 64 + threadIdx.x], rsum[threadIdx.x]);
    else if (threadIdx.x < 128)
        atomicAdd(&cs[p * NROW + cj * 64 + (threadIdx.x - 64)], csum[threadIdx.x - 64]);
}

// ---- K10: final loss reduction ----
__global__ void k10_loss(const float* __restrict__ diag, const float* __restrict__ rs,
                         const float* __restrict__ cs, float* __restrict__ outp) {
    float acc = 0.f;
    for (int i = threadIdx.x; i < 3 * NROW; i += 256)
        acc += 2.f * diag[i] - logf(rs[i]) - logf(cs[i]);
    int lane = threadIdx.x & 63, wv = threadIdx.x >> 6;
    for (int o = 32; o; o >>= 1) acc += __shfl_down(acc, o);
    __shared__ float red[4];
    if (lane == 0) red[wv] = acc;
    __syncthreads();
    if (threadIdx.x == 0) {
        float tot = red[0] + red[1] + red[2] + red[3];
        // loss = -(1/3) * sum_p ((mean(diag-log rs) + mean(diag-log cs))/2)
        outp[(size_t)NROW * 768] = -tot / (NROW * 6.0f);
    }
}

extern "C" void kernel_launch(void* const* d_in, const int* in_sizes, int n_in,
                              void* d_out, int out_size, void* d_ws, size_t ws_size,
                              hipStream_t stream) {
    const float* t   = (const float*)d_in[0];
    const float* a   = (const float*)d_in[1];
    const float* v   = (const float*)d_in[2];
    const float* Wfc = (const float*)d_in[3];
    const float* bfc = (const float*)d_in[4];
    const float* Wh  = (const float*)d_in[5];
    const float* bh  = (const float*)d_in[6];
    float* outp = (float*)d_out;
    float* ws = (float*)d_ws;

    float* sq   = ws;                    // 12288
    float* d2   = sq + 12288;            // 64*192*192 = 2359296
    float* H    = d2 + 2359296;          // 2359296
    float* degE = H + 2359296;           // 12288
    float* degV = degE + 12288;          // 12288
    float* X    = degV + 12288;          // 64*192*256 = 3145728
    float* E    = X + 3145728;           // 3145728
    float* Y    = E + 3145728;           // 3145728
    float* inv  = Y + 3145728;           // 12288
    float* rs   = inv + 12288;           // 12288
    float* cs   = rs + 12288;            // 12288
    float* diag = cs + 12288;            // 12288

    k0_sq  <<<3072, 256, 0, stream>>>(t, a, v, sq);
    k1_d2  <<<dim3(9, 64), 256, 0, stream>>>(t, a, v, sq, d2);
    k2_topk<<<48, 256, 0, stream>>>(d2, H);
    k_deg  <<<96, 256, 0, stream>>>(H, degE, degV);
    k3_x   <<<dim3(4, 192), 256, 0, stream>>>(t, a, v, Wfc, bfc, X);
    k4_E   <<<dim3(4, 3, 64), 256, 0, stream>>>(H, X, degE, E);
    k5_Y   <<<dim3(4, 3, 64), 256, 0, stream>>>(H, E, degV, Y);
    k6_out <<<dim3(4, 192), 256, 0, stream>>>(Y, Wh, bh, outp);
    k7_norm<<<3072, 256, 0, stream>>>(outp, inv);
    k8_zero<<<48, 256, 0, stream>>>(rs, cs);
    k9_sim <<<dim3(64, 64, 3), 256, 0, stream>>>(outp, inv, rs, cs, diag);
    k10_loss<<<1, 256, 0, stream>>>(diag, rs, cs, outp);
}

// Round 2
// 468.028 us; speedup vs baseline: 1.7984x; 1.7984x over previous
//
#include <hip/hip_runtime.h>
#include <math.h>

// Problem constants (from reference): D=64 dialogues, L=64, DIM=512, G=256
// m = 3*L = 192 nodes/hyperedges per dialogue, k = 12, N = D*L = 4096
#define NDIAL 64
#define LUTT  64
#define M3    192
#define DIMF  512
#define GDIM  256
#define NROW  4096
#define TOPK  12
#define INV_TAU (1.0f/0.07f)

typedef __attribute__((ext_vector_type(8))) short bf16x8;
typedef __attribute__((ext_vector_type(4))) float f32x4;

__device__ __forceinline__ ushort f2bf(float f) {
    unsigned u = __float_as_uint(f);
    unsigned r = (u + 0x7fff + ((u >> 16) & 1)) >> 16;   // RNE
    return (ushort)r;
}

// ---------------------------------------------------------------------------
// Generic fp32 64x64 tile GEMM helper. 256 threads, each computes 4x4.
// TA: A element (m,k) at A[k*lda+m] (transposed source)
// TB: B element (k,n) at B[n*ldb+k] (transposed source, i.e. B rows are "n")
// ---------------------------------------------------------------------------
template<int KDIM, bool TA, bool TB>
__device__ __forceinline__ void mm64(
    const float* __restrict__ A, int lda,
    const float* __restrict__ B, int ldb,
    float acc[4][4])
{
    __shared__ float As[64][33];
    __shared__ float Bs[32][68];
    const int tid = threadIdx.x;
    const int tx = tid & 15, ty = tid >> 4;

#pragma unroll
    for (int r = 0; r < 4; r++)
#pragma unroll
        for (int c = 0; c < 4; c++) acc[r][c] = 0.f;

    for (int k0 = 0; k0 < KDIM; k0 += 32) {
        if (!TA) {
#pragma unroll
            for (int i = 0; i < 2; i++) {
                int f = tid + i * 256;
                int m = f >> 3, k4 = f & 7;
                const float4 v4 = *(const float4*)(A + (size_t)m * lda + k0 + k4 * 4);
                As[m][k4 * 4 + 0] = v4.x;
                As[m][k4 * 4 + 1] = v4.y;
                As[m][k4 * 4 + 2] = v4.z;
                As[m][k4 * 4 + 3] = v4.w;
            }
        } else {
#pragma unroll
            for (int i = 0; i < 2; i++) {
                int f = tid + i * 256;
                int k = f >> 4, m4 = f & 15;
                const float4 v4 = *(const float4*)(A + (size_t)(k0 + k) * lda + m4 * 4);
                As[m4 * 4 + 0][k] = v4.x;
                As[m4 * 4 + 1][k] = v4.y;
                As[m4 * 4 + 2][k] = v4.z;
                As[m4 * 4 + 3][k] = v4.w;
            }
        }
        if (!TB) {
#pragma unroll
            for (int i = 0; i < 2; i++) {
                int f = tid + i * 256;
                int k = f >> 4, n4 = f & 15;
                float4 v4 = *(const float4*)(B + (size_t)(k0 + k) * ldb + n4 * 4);
                *(float4*)&Bs[k][n4 * 4] = v4;
            }
        } else {
#pragma unroll
            for (int i = 0; i < 2; i++) {
                int f = tid + i * 256;
                int n = f >> 3, k4 = f & 7;
                const float4 v4 = *(const float4*)(B + (size_t)n * ldb + k0 + k4 * 4);
                Bs[k4 * 4 + 0][n] = v4.x;
                Bs[k4 * 4 + 1][n] = v4.y;
                Bs[k4 * 4 + 2][n] = v4.z;
                Bs[k4 * 4 + 3][n] = v4.w;
            }
        }
        __syncthreads();
#pragma unroll
        for (int kk = 0; kk < 32; kk++) {
            float4 b = *(const float4*)&Bs[kk][tx * 4];
#pragma unroll
            for (int r = 0; r < 4; r++) {
                float av = As[ty * 4 + r][kk];
                acc[r][0] += av * b.x;
                acc[r][1] += av * b.y;
                acc[r][2] += av * b.z;
                acc[r][3] += av * b.w;
            }
        }
        __syncthreads();
    }
}

__device__ __forceinline__ const float* node_ptr(const float* t, const float* a,
                                                 const float* v, int d, int j) {
    int mod = j >> 6, i = j & 63;
    const float* base = (mod == 0) ? t : (mod == 1) ? a : v;
    return base + (size_t)(d * 64 + i) * DIMF;
}

// ---- K0: per-node squared norms (wave per row) ----
__global__ void k0_sq(const float* __restrict__ t, const float* __restrict__ a,
                      const float* __restrict__ v, float* __restrict__ sq) {
    int lane = threadIdx.x & 63, wv = threadIdx.x >> 6;
    int n = blockIdx.x * 4 + wv;
    int d = n / M3, j = n % M3;
    const float4* s4 = (const float4*)node_ptr(t, a, v, d, j);
    float s = 0.f;
#pragma unroll
    for (int q = 0; q < 2; q++) {
        float4 x = s4[lane + q * 64];
        s += x.x * x.x + x.y * x.y + x.z * x.z + x.w * x.w;
    }
    for (int o = 32; o; o >>= 1) s += __shfl_down(s, o);
    if (lane == 0) sq[n] = s;
}

// ---- K1: clamped squared distances per dialogue ----
__global__ void k1_d2(const float* __restrict__ t, const float* __restrict__ a,
                      const float* __restrict__ v, const float* __restrict__ sq,
                      float* __restrict__ d2) {
    int tileid = blockIdx.x;
    int d = blockIdx.y;
    int bi = tileid / 3, bj = tileid % 3;
    const float* A = ((bi == 0) ? t : (bi == 1) ? a : v) + (size_t)d * 64 * DIMF;
    const float* B = ((bj == 0) ? t : (bj == 1) ? a : v) + (size_t)d * 64 * DIMF;
    float acc[4][4];
    mm64<DIMF, false, true>(A, DIMF, B, DIMF, acc);
    int tx = threadIdx.x & 15, ty = threadIdx.x >> 4;
    const float* sqd = sq + d * M3;
    float* outp = d2 + (size_t)d * M3 * M3;
#pragma unroll
    for (int r = 0; r < 4; r++)
#pragma unroll
        for (int c = 0; c < 4; c++) {
            int il = bi * 64 + ty * 4 + r;
            int jl = bj * 64 + tx * 4 + c;
            float vv = sqd[il] + sqd[jl] - 2.f * acc[r][c];
            outp[(size_t)il * M3 + jl] = fmaxf(vv, 0.f);
        }
}

// ---- K2: top-12 smallest per row + build H ----
__global__ void k2_topk(const float* __restrict__ d2, float* __restrict__ H) {
    int r = blockIdx.x * 256 + threadIdx.x;
    int d = r / M3, e = r % M3;
    const float* row = d2 + ((size_t)d * M3 + e) * M3;
    float bd[TOPK];
    int bx[TOPK];
#pragma unroll
    for (int i = 0; i < TOPK; i++) { bd[i] = 3.4e38f; bx[i] = -1; }
    for (int n = 0; n < M3; n++) {
        float vv = row[n];
        if (vv < bd[TOPK - 1]) {
            int p = TOPK - 1;
            while (p > 0 && bd[p - 1] > vv) {
                bd[p] = bd[p - 1]; bx[p] = bx[p - 1]; p--;
            }
            bd[p] = vv; bx[p] = n;
        }
    }
    float* Hrow = H + ((size_t)d * M3 + e) * M3;
    for (int n = 0; n < M3; n++) Hrow[n] = 0.f;
#pragma unroll
    for (int i = 0; i < TOPK; i++) Hrow[bx[i]] = 1.f;
    int u = e / 3;
    Hrow[u] = 1.f; Hrow[u + 64] = 1.f; Hrow[u + 128] = 1.f;
}

// ---- Kdeg: deg_e (row sums) and deg_v (col sums) of H ----
__global__ void k_deg(const float* __restrict__ H, float* __restrict__ degE,
                      float* __restrict__ degV) {
    int tid = blockIdx.x * 256 + threadIdx.x;
    if (tid < 12288) {
        int d = tid / M3, e = tid % M3;
        const float* row = H + ((size_t)d * M3 + e) * M3;
        float s = 0.f;
        for (int n = 0; n < M3; n++) s += row[n];
        degE[tid] = s;
    } else if (tid < 24576) {
        int q = tid - 12288;
        int d = q / M3, n = q % M3;
        const float* col = H + (size_t)d * M3 * M3 + n;
        float s = 0.f;
        for (int e = 0; e < M3; e++) s += col[(size_t)e * M3];
        degV[q] = s;
    }
}

// ---- K3: X = feat @ W_fc + b_fc ----
__global__ void k3_x(const float* __restrict__ t, const float* __restrict__ a,
                     const float* __restrict__ v, const float* __restrict__ Wfc,
                     const float* __restrict__ bfc, float* __restrict__ X) {
    int cb = blockIdx.x, rt = blockIdx.y;
    int d = rt / 3, mod = rt % 3;
    const float* A = ((mod == 0) ? t : (mod == 1) ? a : v) + (size_t)d * 64 * DIMF;
    const float* B = Wfc + cb * 64;
    float acc[4][4];
    mm64<DIMF, false, false>(A, DIMF, B, GDIM, acc);
    int tx = threadIdx.x & 15, ty = threadIdx.x >> 4;
#pragma unroll
    for (int r = 0; r < 4; r++)
#pragma unroll
        for (int c = 0; c < 4; c++) {
            int i = ty * 4 + r;
            int col = cb * 64 + tx * 4 + c;
            X[((size_t)d * M3 + mod * 64 + i) * GDIM + col] = acc[r][c] + bfc[col];
        }
}

// ---- K4: E = (H @ X) / deg_e ----
__global__ void k4_E(const float* __restrict__ H, const float* __restrict__ X,
                     const float* __restrict__ degE, float* __restrict__ E) {
    int cb = blockIdx.x, bi = blockIdx.y, d = blockIdx.z;
    const float* A = H + (size_t)d * M3 * M3 + (size_t)(bi * 64) * M3;
    const float* B = X + (size_t)d * M3 * GDIM + cb * 64;
    float acc[4][4];
    mm64<M3, false, false>(A, M3, B, GDIM, acc);
    int tx = threadIdx.x & 15, ty = threadIdx.x >> 4;
#pragma unroll
    for (int r = 0; r < 4; r++) {
        int e = bi * 64 + ty * 4 + r;
        float dg = degE[d * M3 + e];
#pragma unroll
        for (int c = 0; c < 4; c++) {
            int col = cb * 64 + tx * 4 + c;
            E[((size_t)d * M3 + e) * GDIM + col] = acc[r][c] / dg;
        }
    }
}

// ---- K5: Y = (H^T @ E) / deg_v ----
__global__ void k5_Y(const float* __restrict__ H, const float* __restrict__ E,
                     const float* __restrict__ degV, float* __restrict__ Y) {
    int cb = blockIdx.x, bi = blockIdx.y, d = blockIdx.z;
    const float* A = H + (size_t)d * M3 * M3 + bi * 64;
    const float* B = E + (size_t)d * M3 * GDIM + cb * 64;
    float acc[4][4];
    mm64<M3, true, false>(A, M3, B, GDIM, acc);
    int tx = threadIdx.x & 15, ty = threadIdx.x >> 4;
#pragma unroll
    for (int r = 0; r < 4; r++) {
        int n = bi * 64 + ty * 4 + r;
        float dg = degV[d * M3 + n];
#pragma unroll
        for (int c = 0; c < 4; c++) {
            int col = cb * 64 + tx * 4 + c;
            Y[((size_t)d * M3 + n) * GDIM + col] = acc[r][c] / dg;
        }
    }
}

// ---- K6: out = relu(Y @ W_h + b_h), scattered as [tn an vn] ----
__global__ void k6_out(const float* __restrict__ Y, const float* __restrict__ Wh,
                       const float* __restrict__ bh, float* __restrict__ outp) {
    int cb = blockIdx.x, rt = blockIdx.y;
    int d = rt / 3, mod = rt % 3;
    const float* A = Y + ((size_t)d * M3 + mod * 64) * GDIM;
    const float* B = Wh + cb * 64;
    float acc[4][4];
    mm64<GDIM, false, false>(A, GDIM, B, GDIM, acc);
    int tx = threadIdx.x & 15, ty = threadIdx.x >> 4;
#pragma unroll
    for (int r = 0; r < 4; r++)
#pragma unroll
        for (int c = 0; c < 4; c++) {
            int i = ty * 4 + r;
            int col = cb * 64 + tx * 4 + c;
            float vv = acc[r][c] + bh[col];
            outp[(size_t)(d * 64 + i) * 768 + mod * GDIM + col] = fmaxf(vv, 0.f);
        }
}

// ---- K7: normalize rows and write bf16 xnb[3][4096][256] ----
__global__ void k7_norm(const float* __restrict__ outp, ushort* __restrict__ xnb) {
    int lane = threadIdx.x & 63, wv = threadIdx.x >> 6;
    int idx = blockIdx.x * 4 + wv;               // 0..12287
    int p = idx / NROW, r = idx % NROW;
    const float4* src = (const float4*)(outp + (size_t)r * 768 + p * GDIM);
    float4 x = src[lane];
    float s = x.x * x.x + x.y * x.y + x.z * x.z + x.w * x.w;
#pragma unroll
    for (int o = 1; o < 64; o <<= 1) s += __shfl_xor(s, o);
    float inv = 1.f / (sqrtf(s) + 1e-8f);
    ushort4 u;
    u.x = f2bf(x.x * inv);
    u.y = f2bf(x.y * inv);
    u.z = f2bf(x.z * inv);
    u.w = f2bf(x.w * inv);
    *(ushort4*)&xnb[((size_t)p * NROW + r) * GDIM + lane * 4] = u;
}

// ---- K8: zero the row/col exp-sum accumulators ----
__global__ void k8_zero(float* __restrict__ rs, float* __restrict__ cs) {
    int i = blockIdx.x * 256 + threadIdx.x;
    if (i < 3 * NROW) { rs[i] = 0.f; cs[i] = 0.f; }
}

// ---- K9: bf16 MFMA sim tiles; accumulate exp row/col sums + diagonal ----
// |sim| <= 1/tau = 14.29 -> exp never overflows fp32; no max-subtraction.
// 128x128 tile per block, 4 waves, each wave 64x64 via 4x4 mfma_16x16x32 frags.
#define TILE 128
#define BK   32
#define LDK  40   // padded LDS stride (bf16 elems); 80B = 5*16B -> aligned, 2-way max
__global__ __launch_bounds__(256) void k9_mfma(const ushort* __restrict__ xnb,
                                               float* __restrict__ rs,
                                               float* __restrict__ cs,
                                               float* __restrict__ diag) {
    int cj = blockIdx.x, ci = blockIdx.y, p = blockIdx.z;
    int px = (p == 2) ? 1 : 0;
    int py = (p == 0) ? 1 : 2;
    const ushort* A = xnb + ((size_t)px * NROW + ci * TILE) * GDIM;
    const ushort* B = xnb + ((size_t)py * NROW + cj * TILE) * GDIM;

    __shared__ __align__(16) ushort As[TILE * LDK];
    __shared__ __align__(16) ushort Bs[TILE * LDK];

    const int tid = threadIdx.x;
    const int lane = tid & 63, w = tid >> 6;
    const int wrow = w >> 1, wcol = w & 1;
    const int qd = lane >> 4, l15 = lane & 15;

    f32x4 acc[4][4] = {};

    for (int k0 = 0; k0 < GDIM; k0 += BK) {
        // stage A,B tiles: 128 rows x 32 k (bf16), 16B per thread per tile half
#pragma unroll
        for (int i = 0; i < 2; i++) {
            int f = tid + i * 256;               // 0..511
            int row = f >> 2, c8 = f & 3;
            *(float4*)&As[row * LDK + c8 * 8] =
                *(const float4*)&A[(size_t)row * GDIM + k0 + c8 * 8];
            *(float4*)&Bs[row * LDK + c8 * 8] =
                *(const float4*)&B[(size_t)row * GDIM + k0 + c8 * 8];
        }
        __syncthreads();

        bf16x8 af[4], bf[4];
#pragma unroll
        for (int fm = 0; fm < 4; fm++)
            af[fm] = *(const bf16x8*)&As[(wrow * 64 + fm * 16 + l15) * LDK + qd * 8];
#pragma unroll
        for (int fn = 0; fn < 4; fn++)
            bf[fn] = *(const bf16x8*)&Bs[(wcol * 64 + fn * 16 + l15) * LDK + qd * 8];
#pragma unroll
        for (int fm = 0; fm < 4; fm++)
#pragma unroll
            for (int fn = 0; fn < 4; fn++)
                acc[fm][fn] = __builtin_amdgcn_mfma_f32_16x16x32_bf16(
                    af[fm], bf[fn], acc[fm][fn], 0, 0, 0);
        __syncthreads();
    }

    // epilogue: exp, row/col partial sums, diagonal capture
    float rloc[4][4] = {};   // [fm][reg] -> row = wrow*64+fm*16+qd*4+reg
    float cloc[4] = {};      // [fn]      -> col = wcol*64+fn*16+l15
#pragma unroll
    for (int fm = 0; fm < 4; fm++)
#pragma unroll
        for (int fn = 0; fn < 4; fn++)
#pragma unroll
            for (int rg = 0; rg < 4; rg++) {
                float s = acc[fm][fn][rg] * INV_TAU;
                float e = __expf(s);
                rloc[fm][rg] += e;
                cloc[fn] += e;
                if (ci == cj && wrow == wcol && fm == fn && (qd * 4 + rg) == l15)
                    diag[p * NROW + ci * TILE + wrow * 64 + fm * 16 + qd * 4 + rg] = s;
            }
    // rows: reduce across the 16 lanes of a quad (cols), lanes l15==0 commit
#pragma unroll
    for (int fm = 0; fm < 4; fm++)
#pragma unroll
        for (int rg = 0; rg < 4; rg++) {
            float s = rloc[fm][rg];
            s += __shfl_xor(s, 1);
            s += __shfl_xor(s, 2);
            s += __shfl_xor(s, 4);
            s += __shfl_xor(s, 8);
            if (l15 == 0)
                atomicAdd(&rs[p * NROW + ci * TILE + wrow * 64 + fm * 16 + qd * 4 + rg], s);
        }
    // cols: reduce across quads (rows), lanes qd==0 commit
#pragma unroll
    for (int fn = 0; fn < 4; fn++) {
        float s = cloc[fn];
        s += __shfl_xor(s, 16);
        s += __shfl_xor(s, 32);
        if (qd == 0)
            atomicAdd(&cs[p * NROW + cj * TILE + wcol * 64 + fn * 16 + l15], s);
    }
}

// ---- K10: final loss reduction ----
__global__ void k10_loss(const float* __restrict__ diag, const float* __restrict__ rs,
                         const float* __restrict__ cs, float* __restrict__ outp) {
    float acc = 0.f;
    for (int i = threadIdx.x; i < 3 * NROW; i += 256)
        acc += 2.f * diag[i] - logf(rs[i]) - logf(cs[i]);
    int lane = threadIdx.x & 63, wv = threadIdx.x >> 6;
    for (int o = 32; o; o >>= 1) acc += __shfl_down(acc, o);
    __shared__ float red[4];
    if (lane == 0) red[wv] = acc;
    __syncthreads();
    if (threadIdx.x == 0) {
        float tot = red[0] + red[1] + red[2] + red[3];
        outp[(size_t)NROW * 768] = -tot / (NROW * 6.0f);
    }
}

extern "C" void kernel_launch(void* const* d_in, const int* in_sizes, int n_in,
                              void* d_out, int out_size, void* d_ws, size_t ws_size,
                              hipStream_t stream) {
    const float* t   = (const float*)d_in[0];
    const float* a   = (const float*)d_in[1];
    const float* v   = (const float*)d_in[2];
    const float* Wfc = (const float*)d_in[3];
    const float* bfc = (const float*)d_in[4];
    const float* Wh  = (const float*)d_in[5];
    const float* bh  = (const float*)d_in[6];
    float* outp = (float*)d_out;
    float* ws = (float*)d_ws;

    float* sq   = ws;                    // 12288
    float* d2   = sq + 12288;            // 2359296 (dead after k2 -> reused as xnb)
    float* H    = d2 + 2359296;          // 2359296
    float* degE = H + 2359296;           // 12288
    float* degV = degE + 12288;          // 12288
    float* X    = degV + 12288;          // 3145728
    float* E    = X + 3145728;           // 3145728
    float* Y    = E + 3145728;           // 3145728
    float* rs   = Y + 3145728;           // 12288
    float* cs   = rs + 12288;            // 12288
    float* diag = cs + 12288;            // 12288
    ushort* xnb = (ushort*)d2;           // 3*4096*256 bf16 = 6.3 MB (fits in d2)

    k0_sq  <<<3072, 256, 0, stream>>>(t, a, v, sq);
    k1_d2  <<<dim3(9, 64), 256, 0, stream>>>(t, a, v, sq, d2);
    k2_topk<<<48, 256, 0, stream>>>(d2, H);
    k_deg  <<<96, 256, 0, stream>>>(H, degE, degV);
    k3_x   <<<dim3(4, 192), 256, 0, stream>>>(t, a, v, Wfc, bfc, X);
    k4_E   <<<dim3(4, 3, 64), 256, 0, stream>>>(H, X, degE, E);
    k5_Y   <<<dim3(4, 3, 64), 256, 0, stream>>>(H, E, degV, Y);
    k6_out <<<dim3(4, 192), 256, 0, stream>>>(Y, Wh, bh, outp);
    k7_norm<<<3072, 256, 0, stream>>>(outp, xnb);
    k8_zero<<<48, 256, 0, stream>>>(rs, cs);
    k9_mfma<<<dim3(32, 32, 3), 256, 0, stream>>>(xnb, rs, cs, diag);
    k10_loss<<<1, 256, 0, stream>>>(diag, rs, cs, outp);
}

// Round 3
// 364.991 us; speedup vs baseline: 2.3061x; 1.2823x over previous
//
#include <hip/hip_runtime.h>
#include <math.h>

// Problem constants (from reference): D=64 dialogues, L=64, DIM=512, G=256
// m = 3*L = 192 nodes/hyperedges per dialogue, k = 12, N = D*L = 4096
#define NDIAL 64
#define LUTT  64
#define M3    192
#define DIMF  512
#define GDIM  256
#define NROW  4096
#define TOPK  12
#define INV_TAU (1.0f/0.07f)

typedef __attribute__((ext_vector_type(8))) short bf16x8;
typedef __attribute__((ext_vector_type(4))) float f32x4;

__device__ __forceinline__ ushort f2bf(float f) {
    unsigned u = __float_as_uint(f);
    unsigned r = (u + 0x7fff + ((u >> 16) & 1)) >> 16;   // RNE
    return (ushort)r;
}

// ---------------------------------------------------------------------------
// Generic fp32 64x64 tile GEMM helper. 256 threads, each computes 4x4.
// ---------------------------------------------------------------------------
template<int KDIM, bool TA, bool TB>
__device__ __forceinline__ void mm64(
    const float* __restrict__ A, int lda,
    const float* __restrict__ B, int ldb,
    float acc[4][4])
{
    __shared__ float As[64][33];
    __shared__ float Bs[32][68];
    const int tid = threadIdx.x;
    const int tx = tid & 15, ty = tid >> 4;

#pragma unroll
    for (int r = 0; r < 4; r++)
#pragma unroll
        for (int c = 0; c < 4; c++) acc[r][c] = 0.f;

    for (int k0 = 0; k0 < KDIM; k0 += 32) {
        if (!TA) {
#pragma unroll
            for (int i = 0; i < 2; i++) {
                int f = tid + i * 256;
                int m = f >> 3, k4 = f & 7;
                const float4 v4 = *(const float4*)(A + (size_t)m * lda + k0 + k4 * 4);
                As[m][k4 * 4 + 0] = v4.x;
                As[m][k4 * 4 + 1] = v4.y;
                As[m][k4 * 4 + 2] = v4.z;
                As[m][k4 * 4 + 3] = v4.w;
            }
        } else {
#pragma unroll
            for (int i = 0; i < 2; i++) {
                int f = tid + i * 256;
                int k = f >> 4, m4 = f & 15;
                const float4 v4 = *(const float4*)(A + (size_t)(k0 + k) * lda + m4 * 4);
                As[m4 * 4 + 0][k] = v4.x;
                As[m4 * 4 + 1][k] = v4.y;
                As[m4 * 4 + 2][k] = v4.z;
                As[m4 * 4 + 3][k] = v4.w;
            }
        }
        if (!TB) {
#pragma unroll
            for (int i = 0; i < 2; i++) {
                int f = tid + i * 256;
                int k = f >> 4, n4 = f & 15;
                float4 v4 = *(const float4*)(B + (size_t)(k0 + k) * ldb + n4 * 4);
                *(float4*)&Bs[k][n4 * 4] = v4;
            }
        } else {
#pragma unroll
            for (int i = 0; i < 2; i++) {
                int f = tid + i * 256;
                int n = f >> 3, k4 = f & 7;
                const float4 v4 = *(const float4*)(B + (size_t)n * ldb + k0 + k4 * 4);
                Bs[k4 * 4 + 0][n] = v4.x;
                Bs[k4 * 4 + 1][n] = v4.y;
                Bs[k4 * 4 + 2][n] = v4.z;
                Bs[k4 * 4 + 3][n] = v4.w;
            }
        }
        __syncthreads();
#pragma unroll
        for (int kk = 0; kk < 32; kk++) {
            float4 b = *(const float4*)&Bs[kk][tx * 4];
#pragma unroll
            for (int r = 0; r < 4; r++) {
                float av = As[ty * 4 + r][kk];
                acc[r][0] += av * b.x;
                acc[r][1] += av * b.y;
                acc[r][2] += av * b.z;
                acc[r][3] += av * b.w;
            }
        }
        __syncthreads();
    }
}

__device__ __forceinline__ const float* node_ptr(const float* t, const float* a,
                                                 const float* v, int d, int j) {
    int mod = j >> 6, i = j & 63;
    const float* base = (mod == 0) ? t : (mod == 1) ? a : v;
    return base + (size_t)(d * 64 + i) * DIMF;
}

// ---- K0: per-node squared norms (wave per row) ----
__global__ void k0_sq(const float* __restrict__ t, const float* __restrict__ a,
                      const float* __restrict__ v, float* __restrict__ sq) {
    int lane = threadIdx.x & 63, wv = threadIdx.x >> 6;
    int n = blockIdx.x * 4 + wv;
    int d = n / M3, j = n % M3;
    const float4* s4 = (const float4*)node_ptr(t, a, v, d, j);
    float s = 0.f;
#pragma unroll
    for (int q = 0; q < 2; q++) {
        float4 x = s4[lane + q * 64];
        s += x.x * x.x + x.y * x.y + x.z * x.z + x.w * x.w;
    }
    for (int o = 32; o; o >>= 1) s += __shfl_down(s, o);
    if (lane == 0) sq[n] = s;
}

// ---- K1: clamped squared distances; symmetric -> 6 of 9 tiles, mirror write ----
__global__ void k1_d2(const float* __restrict__ t, const float* __restrict__ a,
                      const float* __restrict__ v, const float* __restrict__ sq,
                      float* __restrict__ d2) {
    int tileid = blockIdx.x;             // 0..5 -> (bi,bj) upper triangle
    int d = blockIdx.y;
    int bi = (tileid < 3) ? 0 : (tileid < 5) ? 1 : 2;
    int bj = (tileid < 3) ? tileid : (tileid < 5) ? tileid - 2 : 2;
    const float* A = ((bi == 0) ? t : (bi == 1) ? a : v) + (size_t)d * 64 * DIMF;
    const float* B = ((bj == 0) ? t : (bj == 1) ? a : v) + (size_t)d * 64 * DIMF;
    float acc[4][4];
    mm64<DIMF, false, true>(A, DIMF, B, DIMF, acc);
    int tx = threadIdx.x & 15, ty = threadIdx.x >> 4;
    const float* sqd = sq + d * M3;
    float* outp = d2 + (size_t)d * M3 * M3;
#pragma unroll
    for (int r = 0; r < 4; r++)
#pragma unroll
        for (int c = 0; c < 4; c++) {
            int il = bi * 64 + ty * 4 + r;
            int jl = bj * 64 + tx * 4 + c;
            float vv = fmaxf(sqd[il] + sqd[jl] - 2.f * acc[r][c], 0.f);
            outp[(size_t)il * M3 + jl] = vv;
            if (bi != bj) outp[(size_t)jl * M3 + il] = vv;
        }
}

// ---- K2: wave-per-row top-12 + H build + fused degrees ----
// Lane l owns columns {l, l+64, l+128}. 12 rounds of lexicographic (val,idx)
// butterfly min reproduce the stable lower-index-wins-ties selection.
__global__ void k2_topk(const float* __restrict__ d2, float* __restrict__ H,
                        float* __restrict__ degE, float* __restrict__ degV) {
    int lane = threadIdx.x & 63, wv = threadIdx.x >> 6;
    int r = blockIdx.x * 4 + wv;                 // 0..12287
    int d = r / M3, e = r % M3;
    const float* row = d2 + (size_t)r * M3;
    float w0 = row[lane], w1 = row[lane + 64], w2 = row[lane + 128];
    bool s0 = false, s1 = false, s2 = false;
#pragma unroll
    for (int it = 0; it < TOPK; it++) {
        float bv = w0; int bi = lane;
        if (w1 < bv) { bv = w1; bi = lane + 64; }
        if (w2 < bv) { bv = w2; bi = lane + 128; }
#pragma unroll
        for (int o = 1; o < 64; o <<= 1) {
            float ov = __shfl_xor(bv, o);
            int   oi = __shfl_xor(bi, o);
            if (ov < bv || (ov == bv && oi < bi)) { bv = ov; bi = oi; }
        }
        if (bi == lane)            { s0 = true; w0 = 3.4e38f; }
        else if (bi == lane + 64)  { s1 = true; w1 = 3.4e38f; }
        else if (bi == lane + 128) { s2 = true; w2 = 3.4e38f; }
    }
    int u = e / 3;
    if (lane == u) { s0 = true; s1 = true; s2 = true; }
    float f0 = s0 ? 1.f : 0.f, f1 = s1 ? 1.f : 0.f, f2 = s2 ? 1.f : 0.f;
    float* Hrow = H + (size_t)r * M3;
    Hrow[lane] = f0; Hrow[lane + 64] = f1; Hrow[lane + 128] = f2;
    float cnt = f0 + f1 + f2;
#pragma unroll
    for (int o = 1; o < 64; o <<= 1) cnt += __shfl_xor(cnt, o);
    if (lane == 0) degE[r] = cnt;
    float* dv = degV + d * M3;
    if (s0) atomicAdd(&dv[lane], 1.f);
    if (s1) atomicAdd(&dv[lane + 64], 1.f);
    if (s2) atomicAdd(&dv[lane + 128], 1.f);
}

// ---- K3: X = feat @ W_fc + b_fc ----
__global__ void k3_x(const float* __restrict__ t, const float* __restrict__ a,
                     const float* __restrict__ v, const float* __restrict__ Wfc,
                     const float* __restrict__ bfc, float* __restrict__ X) {
    int cb = blockIdx.x, rt = blockIdx.y;
    int d = rt / 3, mod = rt % 3;
    const float* A = ((mod == 0) ? t : (mod == 1) ? a : v) + (size_t)d * 64 * DIMF;
    const float* B = Wfc + cb * 64;
    float acc[4][4];
    mm64<DIMF, false, false>(A, DIMF, B, GDIM, acc);
    int tx = threadIdx.x & 15, ty = threadIdx.x >> 4;
#pragma unroll
    for (int r = 0; r < 4; r++)
#pragma unroll
        for (int c = 0; c < 4; c++) {
            int i = ty * 4 + r;
            int col = cb * 64 + tx * 4 + c;
            X[((size_t)d * M3 + mod * 64 + i) * GDIM + col] = acc[r][c] + bfc[col];
        }
}

// ---- K4: E = (H @ X) / deg_e ----
__global__ void k4_E(const float* __restrict__ H, const float* __restrict__ X,
                     const float* __restrict__ degE, float* __restrict__ E) {
    int cb = blockIdx.x, bi = blockIdx.y, d = blockIdx.z;
    const float* A = H + (size_t)d * M3 * M3 + (size_t)(bi * 64) * M3;
    const float* B = X + (size_t)d * M3 * GDIM + cb * 64;
    float acc[4][4];
    mm64<M3, false, false>(A, M3, B, GDIM, acc);
    int tx = threadIdx.x & 15, ty = threadIdx.x >> 4;
#pragma unroll
    for (int r = 0; r < 4; r++) {
        int e = bi * 64 + ty * 4 + r;
        float dg = degE[d * M3 + e];
#pragma unroll
        for (int c = 0; c < 4; c++) {
            int col = cb * 64 + tx * 4 + c;
            E[((size_t)d * M3 + e) * GDIM + col] = acc[r][c] / dg;
        }
    }
}

// ---- K5: Y = (H^T @ E) / deg_v ----
__global__ void k5_Y(const float* __restrict__ H, const float* __restrict__ E,
                     const float* __restrict__ degV, float* __restrict__ Y) {
    int cb = blockIdx.x, bi = blockIdx.y, d = blockIdx.z;
    const float* A = H + (size_t)d * M3 * M3 + bi * 64;
    const float* B = E + (size_t)d * M3 * GDIM + cb * 64;
    float acc[4][4];
    mm64<M3, true, false>(A, M3, B, GDIM, acc);
    int tx = threadIdx.x & 15, ty = threadIdx.x >> 4;
#pragma unroll
    for (int r = 0; r < 4; r++) {
        int n = bi * 64 + ty * 4 + r;
        float dg = degV[d * M3 + n];
#pragma unroll
        for (int c = 0; c < 4; c++) {
            int col = cb * 64 + tx * 4 + c;
            Y[((size_t)d * M3 + n) * GDIM + col] = acc[r][c] / dg;
        }
    }
}

// ---- K6: out = relu(Y @ W_h + b_h), scattered as [tn an vn] ----
__global__ void k6_out(const float* __restrict__ Y, const float* __restrict__ Wh,
                       const float* __restrict__ bh, float* __restrict__ outp) {
    int cb = blockIdx.x, rt = blockIdx.y;
    int d = rt / 3, mod = rt % 3;
    const float* A = Y + ((size_t)d * M3 + mod * 64) * GDIM;
    const float* B = Wh + cb * 64;
    float acc[4][4];
    mm64<GDIM, false, false>(A, GDIM, B, GDIM, acc);
    int tx = threadIdx.x & 15, ty = threadIdx.x >> 4;
#pragma unroll
    for (int r = 0; r < 4; r++)
#pragma unroll
        for (int c = 0; c < 4; c++) {
            int i = ty * 4 + r;
            int col = cb * 64 + tx * 4 + c;
            float vv = acc[r][c] + bh[col];
            outp[(size_t)(d * 64 + i) * 768 + mod * GDIM + col] = fmaxf(vv, 0.f);
        }
}

// ---- K7: normalize rows and write bf16 xnb[3][4096][256] ----
__global__ void k7_norm(const float* __restrict__ outp, ushort* __restrict__ xnb) {
    int lane = threadIdx.x & 63, wv = threadIdx.x >> 6;
    int idx = blockIdx.x * 4 + wv;               // 0..12287
    int p = idx / NROW, r = idx % NROW;
    const float4* src = (const float4*)(outp + (size_t)r * 768 + p * GDIM);
    float4 x = src[lane];
    float s = x.x * x.x + x.y * x.y + x.z * x.z + x.w * x.w;
#pragma unroll
    for (int o = 1; o < 64; o <<= 1) s += __shfl_xor(s, o);
    float inv = 1.f / (sqrtf(s) + 1e-8f);
    ushort4 u;
    u.x = f2bf(x.x * inv);
    u.y = f2bf(x.y * inv);
    u.z = f2bf(x.z * inv);
    u.w = f2bf(x.w * inv);
    *(ushort4*)&xnb[((size_t)p * NROW + r) * GDIM + lane * 4] = u;
}

// ---- K8: zero rs/cs exp-sum accumulators + degV ----
__global__ void k8_zero(float* __restrict__ rs, float* __restrict__ cs,
                        float* __restrict__ degV) {
    int i = blockIdx.x * 256 + threadIdx.x;
    if (i < 3 * NROW) { rs[i] = 0.f; cs[i] = 0.f; degV[i] = 0.f; }
}

// ---- K9: bf16 MFMA sim tiles; accumulate exp row/col sums + diagonal ----
#define TILE 128
#define BK   32
#define LDK  40   // padded LDS stride (bf16 elems)
__global__ __launch_bounds__(256) void k9_mfma(const ushort* __restrict__ xnb,
                                               float* __restrict__ rs,
                                               float* __restrict__ cs,
                                               float* __restrict__ diag) {
    int cj = blockIdx.x, ci = blockIdx.y, p = blockIdx.z;
    int px = (p == 2) ? 1 : 0;
    int py = (p == 0) ? 1 : 2;
    const ushort* A = xnb + ((size_t)px * NROW + ci * TILE) * GDIM;
    const ushort* B = xnb + ((size_t)py * NROW + cj * TILE) * GDIM;

    __shared__ __align__(16) ushort As[TILE * LDK];
    __shared__ __align__(16) ushort Bs[TILE * LDK];

    const int tid = threadIdx.x;
    const int lane = tid & 63, w = tid >> 6;
    const int wrow = w >> 1, wcol = w & 1;
    const int qd = lane >> 4, l15 = lane & 15;

    f32x4 acc[4][4] = {};

    for (int k0 = 0; k0 < GDIM; k0 += BK) {
#pragma unroll
        for (int i = 0; i < 2; i++) {
            int f = tid + i * 256;
            int row = f >> 2, c8 = f & 3;
            *(float4*)&As[row * LDK + c8 * 8] =
                *(const float4*)&A[(size_t)row * GDIM + k0 + c8 * 8];
            *(float4*)&Bs[row * LDK + c8 * 8] =
                *(const float4*)&B[(size_t)row * GDIM + k0 + c8 * 8];
        }
        __syncthreads();

        bf16x8 af[4], bf[4];
#pragma unroll
        for (int fm = 0; fm < 4; fm++)
            af[fm] = *(const bf16x8*)&As[(wrow * 64 + fm * 16 + l15) * LDK + qd * 8];
#pragma unroll
        for (int fn = 0; fn < 4; fn++)
            bf[fn] = *(const bf16x8*)&Bs[(wcol * 64 + fn * 16 + l15) * LDK + qd * 8];
#pragma unroll
        for (int fm = 0; fm < 4; fm++)
#pragma unroll
            for (int fn = 0; fn < 4; fn++)
                acc[fm][fn] = __builtin_amdgcn_mfma_f32_16x16x32_bf16(
                    af[fm], bf[fn], acc[fm][fn], 0, 0, 0);
        __syncthreads();
    }

    float rloc[4][4] = {};
    float cloc[4] = {};
#pragma unroll
    for (int fm = 0; fm < 4; fm++)
#pragma unroll
        for (int fn = 0; fn < 4; fn++)
#pragma unroll
            for (int rg = 0; rg < 4; rg++) {
                float s = acc[fm][fn][rg] * INV_TAU;
                float e = __expf(s);
                rloc[fm][rg] += e;
                cloc[fn] += e;
                if (ci == cj && wrow == wcol && fm == fn && (qd * 4 + rg) == l15)
                    diag[p * NROW + ci * TILE + wrow * 64 + fm * 16 + qd * 4 + rg] = s;
            }
#pragma unroll
    for (int fm = 0; fm < 4; fm++)
#pragma unroll
        for (int rg = 0; rg < 4; rg++) {
            float s = rloc[fm][rg];
            s += __shfl_xor(s, 1);
            s += __shfl_xor(s, 2);
            s += __shfl_xor(s, 4);
            s += __shfl_xor(s, 8);
            if (l15 == 0)
                atomicAdd(&rs[p * NROW + ci * TILE + wrow * 64 + fm * 16 + qd * 4 + rg], s);
        }
#pragma unroll
    for (int fn = 0; fn < 4; fn++) {
        float s = cloc[fn];
        s += __shfl_xor(s, 16);
        s += __shfl_xor(s, 32);
        if (qd == 0)
            atomicAdd(&cs[p * NROW + cj * TILE + wcol * 64 + fn * 16 + l15], s);
    }
}

// ---- K10: final loss reduction ----
__global__ void k10_loss(const float* __restrict__ diag, const float* __restrict__ rs,
                         const float* __restrict__ cs, float* __restrict__ outp) {
    float acc = 0.f;
    for (int i = threadIdx.x; i < 3 * NROW; i += 256)
        acc += 2.f * diag[i] - logf(rs[i]) - logf(cs[i]);
    int lane = threadIdx.x & 63, wv = threadIdx.x >> 6;
    for (int o = 32; o; o >>= 1) acc += __shfl_down(acc, o);
    __shared__ float red[4];
    if (lane == 0) red[wv] = acc;
    __syncthreads();
    if (threadIdx.x == 0) {
        float tot = red[0] + red[1] + red[2] + red[3];
        outp[(size_t)NROW * 768] = -tot / (NROW * 6.0f);
    }
}

extern "C" void kernel_launch(void* const* d_in, const int* in_sizes, int n_in,
                              void* d_out, int out_size, void* d_ws, size_t ws_size,
                              hipStream_t stream) {
    const float* t   = (const float*)d_in[0];
    const float* a   = (const float*)d_in[1];
    const float* v   = (const float*)d_in[2];
    const float* Wfc = (const float*)d_in[3];
    const float* bfc = (const float*)d_in[4];
    const float* Wh  = (const float*)d_in[5];
    const float* bh  = (const float*)d_in[6];
    float* outp = (float*)d_out;
    float* ws = (float*)d_ws;

    float* sq   = ws;                    // 12288
    float* d2   = sq + 12288;            // 2359296 (dead after k2 -> reused as xnb)
    float* H    = d2 + 2359296;          // 2359296
    float* degE = H + 2359296;           // 12288
    float* degV = degE + 12288;          // 12288
    float* X    = degV + 12288;          // 3145728
    float* E    = X + 3145728;           // 3145728
    float* Y    = E + 3145728;           // 3145728
    float* rs   = Y + 3145728;           // 12288
    float* cs   = rs + 12288;            // 12288
    float* diag = cs + 12288;            // 12288
    ushort* xnb = (ushort*)d2;           // bf16[3][4096][256], reuses dead d2

    k0_sq  <<<3072, 256, 0, stream>>>(t, a, v, sq);
    k1_d2  <<<dim3(6, 64), 256, 0, stream>>>(t, a, v, sq, d2);
    k8_zero<<<48, 256, 0, stream>>>(rs, cs, degV);
    k2_topk<<<3072, 256, 0, stream>>>(d2, H, degE, degV);
    k3_x   <<<dim3(4, 192), 256, 0, stream>>>(t, a, v, Wfc, bfc, X);
    k4_E   <<<dim3(4, 3, 64), 256, 0, stream>>>(H, X, degE, E);
    k5_Y   <<<dim3(4, 3, 64), 256, 0, stream>>>(H, E, degV, Y);
    k6_out <<<dim3(4, 192), 256, 0, stream>>>(Y, Wh, bh, outp);
    k7_norm<<<3072, 256, 0, stream>>>(outp, xnb);
    k9_mfma<<<dim3(32, 32, 3), 256, 0, stream>>>(xnb, rs, cs, diag);
    k10_loss<<<1, 256, 0, stream>>>(diag, rs, cs, outp);
}

// Round 4
// 319.825 us; speedup vs baseline: 2.6318x; 1.1412x over previous
//
#include <hip/hip_runtime.h>
#include <math.h>

// Problem constants: D=64 dialogues, L=64, DIM=512, G=256
// m = 3*L = 192 nodes/hyperedges per dialogue, k = 12, N = D*L = 4096
#define NDIAL 64
#define M3    192
#define DIMF  512
#define GDIM  256
#define NROW  4096
#define TOPK  12
#define INV_TAU (1.0f/0.07f)

typedef __attribute__((ext_vector_type(8))) short bf16x8;
typedef __attribute__((ext_vector_type(4))) float f32x4;
typedef _Float16 f16x8 __attribute__((ext_vector_type(8)));
typedef _Float16 f16x4v __attribute__((ext_vector_type(4)));

__device__ __forceinline__ ushort f2bf(float f) {
    unsigned u = __float_as_uint(f);
    unsigned r = (u + 0x7fff + ((u >> 16) & 1)) >> 16;   // RNE
    return (ushort)r;
}

// ---------------------------------------------------------------------------
// fp32 64x64 tile GEMM helper (k1 only: top-k selection must stay fp32).
// ---------------------------------------------------------------------------
template<int KDIM, bool TB>
__device__ __forceinline__ void mm64(
    const float* __restrict__ A, int lda,
    const float* __restrict__ B, int ldb,
    float acc[4][4])
{
    __shared__ float As[64][33];
    __shared__ float Bs[32][68];
    const int tid = threadIdx.x;
    const int tx = tid & 15, ty = tid >> 4;

#pragma unroll
    for (int r = 0; r < 4; r++)
#pragma unroll
        for (int c = 0; c < 4; c++) acc[r][c] = 0.f;

    for (int k0 = 0; k0 < KDIM; k0 += 32) {
#pragma unroll
        for (int i = 0; i < 2; i++) {
            int f = tid + i * 256;
            int m = f >> 3, k4 = f & 7;
            const float4 v4 = *(const float4*)(A + (size_t)m * lda + k0 + k4 * 4);
            As[m][k4 * 4 + 0] = v4.x;
            As[m][k4 * 4 + 1] = v4.y;
            As[m][k4 * 4 + 2] = v4.z;
            As[m][k4 * 4 + 3] = v4.w;
        }
        if (!TB) {
#pragma unroll
            for (int i = 0; i < 2; i++) {
                int f = tid + i * 256;
                int k = f >> 4, n4 = f & 15;
                float4 v4 = *(const float4*)(B + (size_t)(k0 + k) * ldb + n4 * 4);
                *(float4*)&Bs[k][n4 * 4] = v4;
            }
        } else {
#pragma unroll
            for (int i = 0; i < 2; i++) {
                int f = tid + i * 256;
                int n = f >> 3, k4 = f & 7;
                const float4 v4 = *(const float4*)(B + (size_t)n * ldb + k0 + k4 * 4);
                Bs[k4 * 4 + 0][n] = v4.x;
                Bs[k4 * 4 + 1][n] = v4.y;
                Bs[k4 * 4 + 2][n] = v4.z;
                Bs[k4 * 4 + 3][n] = v4.w;
            }
        }
        __syncthreads();
#pragma unroll
        for (int kk = 0; kk < 32; kk++) {
            float4 b = *(const float4*)&Bs[kk][tx * 4];
#pragma unroll
            for (int r = 0; r < 4; r++) {
                float av = As[ty * 4 + r][kk];
                acc[r][0] += av * b.x;
                acc[r][1] += av * b.y;
                acc[r][2] += av * b.z;
                acc[r][3] += av * b.w;
            }
        }
        __syncthreads();
    }
}

// ---------------------------------------------------------------------------
// fp16 MFMA GEMM helper: block = 64 rows x (NW*64) cols, NW waves (wave w
// owns col block w). A: [M][K] row-major; B: "B^T layout" [N][K] row-major.
// C/D layout (verified): row = fm*16 + qd*4 + rg, col = w*64 + fn*16 + l15.
// ---------------------------------------------------------------------------
template<int KD, int NW>
__device__ __forceinline__ void hgemm_bt(const _Float16* __restrict__ A, int lda,
                                         const _Float16* __restrict__ B, int ldb,
                                         f32x4 acc[4][4]) {
    __shared__ __align__(16) _Float16 As[64 * 40];
    __shared__ __align__(16) _Float16 Bs[NW * 64 * 40];
    const int tid = threadIdx.x;
    const int lane = tid & 63, w = tid >> 6;
    const int qd = lane >> 4, l15 = lane & 15;

#pragma unroll
    for (int fm = 0; fm < 4; fm++)
#pragma unroll
        for (int fn = 0; fn < 4; fn++)
            acc[fm][fn] = (f32x4){0.f, 0.f, 0.f, 0.f};

    for (int k0 = 0; k0 < KD; k0 += 32) {
        for (int f = tid; f < 256; f += NW * 64) {
            int row = f >> 2, c8 = f & 3;
            *(float4*)&As[row * 40 + c8 * 8] =
                *(const float4*)&A[(size_t)row * lda + k0 + c8 * 8];
        }
#pragma unroll
        for (int i = 0; i < 4; i++) {
            int f = tid + i * NW * 64;
            int row = f >> 2, c8 = f & 3;
            *(float4*)&Bs[row * 40 + c8 * 8] =
                *(const float4*)&B[(size_t)row * ldb + k0 + c8 * 8];
        }
        __syncthreads();
        f16x8 af[4], bfr[4];
#pragma unroll
        for (int fm = 0; fm < 4; fm++)
            af[fm] = *(const f16x8*)&As[(fm * 16 + l15) * 40 + qd * 8];
#pragma unroll
        for (int fn = 0; fn < 4; fn++)
            bfr[fn] = *(const f16x8*)&Bs[(w * 64 + fn * 16 + l15) * 40 + qd * 8];
#pragma unroll
        for (int fm = 0; fm < 4; fm++)
#pragma unroll
            for (int fn = 0; fn < 4; fn++)
                acc[fm][fn] = __builtin_amdgcn_mfma_f32_16x16x32_f16(
                    af[fm], bfr[fn], acc[fm][fn], 0, 0, 0);
        __syncthreads();
    }
}

// ---- Kcvt: fp32 -> fp16 conversions: featb[64][192][512], WfcT, WhT ----
#define F4_FEAT 1572864
#define F4_WFC  32768
#define F4_WHT  16384
__global__ void kcvt(const float* __restrict__ t, const float* __restrict__ a,
                     const float* __restrict__ v, const float* __restrict__ Wfc,
                     const float* __restrict__ Wh, _Float16* __restrict__ featb,
                     _Float16* __restrict__ WfcT, _Float16* __restrict__ WhT) {
    int f = blockIdx.x * 256 + threadIdx.x;
    if (f < F4_FEAT) {
        int e = f * 4;
        int d = e / (M3 * DIMF);
        int rem = e % (M3 * DIMF);
        int n = rem / DIMF, kk = rem % DIMF;
        int mod = n >> 6, i = n & 63;
        const float* src = ((mod == 0) ? t : (mod == 1) ? a : v)
                           + (size_t)(d * 64 + i) * DIMF + kk;
        float4 x = *(const float4*)src;
        f16x4v o = {(_Float16)x.x, (_Float16)x.y, (_Float16)x.z, (_Float16)x.w};
        *(f16x4v*)&featb[e] = o;
    } else if (f < F4_FEAT + F4_WFC) {
        int e = (f - F4_FEAT) * 4;
        int g = e >> 9, kk = e & 511;
        f16x4v o = {(_Float16)Wfc[(size_t)(kk + 0) * GDIM + g],
                    (_Float16)Wfc[(size_t)(kk + 1) * GDIM + g],
                    (_Float16)Wfc[(size_t)(kk + 2) * GDIM + g],
                    (_Float16)Wfc[(size_t)(kk + 3) * GDIM + g]};
        *(f16x4v*)&WfcT[(size_t)g * DIMF + kk] = o;
    } else if (f < F4_FEAT + F4_WFC + F4_WHT) {
        int e = (f - F4_FEAT - F4_WFC) * 4;
        int go = e >> 8, g = e & 255;
        f16x4v o = {(_Float16)Wh[(size_t)(g + 0) * GDIM + go],
                    (_Float16)Wh[(size_t)(g + 1) * GDIM + go],
                    (_Float16)Wh[(size_t)(g + 2) * GDIM + go],
                    (_Float16)Wh[(size_t)(g + 3) * GDIM + go]};
        *(f16x4v*)&WhT[(size_t)go * GDIM + g] = o;
    }
}

__device__ __forceinline__ const float* node_ptr(const float* t, const float* a,
                                                 const float* v, int d, int j) {
    int mod = j >> 6, i = j & 63;
    const float* base = (mod == 0) ? t : (mod == 1) ? a : v;
    return base + (size_t)(d * 64 + i) * DIMF;
}

// ---- K0: per-node squared norms (wave per row) ----
__global__ void k0_sq(const float* __restrict__ t, const float* __restrict__ a,
                      const float* __restrict__ v, float* __restrict__ sq) {
    int lane = threadIdx.x & 63, wv = threadIdx.x >> 6;
    int n = blockIdx.x * 4 + wv;
    int d = n / M3, j = n % M3;
    const float4* s4 = (const float4*)node_ptr(t, a, v, d, j);
    float s = 0.f;
#pragma unroll
    for (int q = 0; q < 2; q++) {
        float4 x = s4[lane + q * 64];
        s += x.x * x.x + x.y * x.y + x.z * x.z + x.w * x.w;
    }
    for (int o = 32; o; o >>= 1) s += __shfl_down(s, o);
    if (lane == 0) sq[n] = s;
}

// ---- K1: clamped squared distances; symmetric -> 6 of 9 tiles ----
__global__ void k1_d2(const float* __restrict__ t, const float* __restrict__ a,
                      const float* __restrict__ v, const float* __restrict__ sq,
                      float* __restrict__ d2) {
    int tileid = blockIdx.x;             // 0..5 upper triangle
    int d = blockIdx.y;
    int bi = (tileid < 3) ? 0 : (tileid < 5) ? 1 : 2;
    int bj = (tileid < 3) ? tileid : (tileid < 5) ? tileid - 2 : 2;
    const float* A = ((bi == 0) ? t : (bi == 1) ? a : v) + (size_t)d * 64 * DIMF;
    const float* B = ((bj == 0) ? t : (bj == 1) ? a : v) + (size_t)d * 64 * DIMF;
    float acc[4][4];
    mm64<DIMF, true>(A, DIMF, B, DIMF, acc);
    int tx = threadIdx.x & 15, ty = threadIdx.x >> 4;
    const float* sqd = sq + d * M3;
    float* outp = d2 + (size_t)d * M3 * M3;
#pragma unroll
    for (int r = 0; r < 4; r++)
#pragma unroll
        for (int c = 0; c < 4; c++) {
            int il = bi * 64 + ty * 4 + r;
            int jl = bj * 64 + tx * 4 + c;
            float vv = fmaxf(sqd[il] + sqd[jl] - 2.f * acc[r][c], 0.f);
            outp[(size_t)il * M3 + jl] = vv;
            if (bi != bj) outp[(size_t)jl * M3 + il] = vv;
        }
}

// ---- K2: wave-per-row top-12 + fp16 H build + fused degrees ----
__global__ void k2_topk(const float* __restrict__ d2, _Float16* __restrict__ Hb,
                        float* __restrict__ degE, float* __restrict__ degV) {
    int lane = threadIdx.x & 63, wv = threadIdx.x >> 6;
    int r = blockIdx.x * 4 + wv;                 // 0..12287
    int d = r / M3, e = r % M3;
    const float* row = d2 + (size_t)r * M3;
    float w0 = row[lane], w1 = row[lane + 64], w2 = row[lane + 128];
    bool s0 = false, s1 = false, s2 = false;
#pragma unroll
    for (int it = 0; it < TOPK; it++) {
        float bv = w0; int bi = lane;
        if (w1 < bv) { bv = w1; bi = lane + 64; }
        if (w2 < bv) { bv = w2; bi = lane + 128; }
#pragma unroll
        for (int o = 1; o < 64; o <<= 1) {
            float ov = __shfl_xor(bv, o);
            int   oi = __shfl_xor(bi, o);
            if (ov < bv || (ov == bv && oi < bi)) { bv = ov; bi = oi; }
        }
        if (bi == lane)            { s0 = true; w0 = 3.4e38f; }
        else if (bi == lane + 64)  { s1 = true; w1 = 3.4e38f; }
        else if (bi == lane + 128) { s2 = true; w2 = 3.4e38f; }
    }
    int u = e / 3;
    if (lane == u) { s0 = true; s1 = true; s2 = true; }
    float f0 = s0 ? 1.f : 0.f, f1 = s1 ? 1.f : 0.f, f2 = s2 ? 1.f : 0.f;
    _Float16* Hrow = Hb + (size_t)r * M3;
    Hrow[lane] = (_Float16)f0;
    Hrow[lane + 64] = (_Float16)f1;
    Hrow[lane + 128] = (_Float16)f2;
    float cnt = f0 + f1 + f2;
#pragma unroll
    for (int o = 1; o < 64; o <<= 1) cnt += __shfl_xor(cnt, o);
    if (lane == 0) degE[r] = cnt;
    float* dv = degV + d * M3;
    if (s0) atomicAdd(&dv[lane], 1.f);
    if (s1) atomicAdd(&dv[lane + 64], 1.f);
    if (s2) atomicAdd(&dv[lane + 128], 1.f);
}

// ---- KT: per-dialogue transpose Hb -> HbT (fp16, via LDS) ----
__global__ void kT_tr(const _Float16* __restrict__ Hb, _Float16* __restrict__ HbT) {
    __shared__ _Float16 tl[M3 * 193];
    int d = blockIdx.x, tid = threadIdx.x;
    const _Float16* src = Hb + (size_t)d * M3 * M3;
    for (int idx = tid; idx < M3 * M3; idx += 256) {
        int e = idx / M3, n = idx % M3;
        tl[n * 193 + e] = src[idx];
    }
    __syncthreads();
    _Float16* dst = HbT + (size_t)d * M3 * M3;
    for (int idx = tid; idx < M3 * M3; idx += 256) {
        int n = idx / M3, e = idx % M3;
        dst[idx] = tl[n * 193 + e];
    }
}

// ---- K3': XT = (feat @ Wfc)^T + bfc, per dialogue. XT[d][g][n] fp16 ----
__global__ void k3_x(const _Float16* __restrict__ WfcT, const _Float16* __restrict__ featb,
                     const float* __restrict__ bfc, _Float16* __restrict__ XT) {
    int gb = blockIdx.x, d = blockIdx.y;
    const _Float16* A = WfcT + (size_t)gb * 64 * DIMF;
    const _Float16* B = featb + (size_t)d * M3 * DIMF;
    f32x4 acc[4][4];
    hgemm_bt<DIMF, 3>(A, DIMF, B, DIMF, acc);
    int lane = threadIdx.x & 63, w = threadIdx.x >> 6;
    int qd = lane >> 4, l15 = lane & 15;
    _Float16* out = XT + (size_t)d * GDIM * M3;
#pragma unroll
    for (int fm = 0; fm < 4; fm++)
#pragma unroll
        for (int rg = 0; rg < 4; rg++) {
            int g = gb * 64 + fm * 16 + qd * 4 + rg;
            float bias = bfc[g];
#pragma unroll
            for (int fn = 0; fn < 4; fn++) {
                int n = w * 64 + fn * 16 + l15;
                out[(size_t)g * M3 + n] = (_Float16)(acc[fm][fn][rg] + bias);
            }
        }
}

// ---- K4': ET = (H @ X)^T / deg_e = XT @ H(B^T).  ET[d][g][e] fp16 ----
__global__ void k4_E(const _Float16* __restrict__ XT, const _Float16* __restrict__ Hb,
                     const float* __restrict__ degE, _Float16* __restrict__ ET) {
    int gb = blockIdx.x, d = blockIdx.y;
    const _Float16* A = XT + (size_t)d * GDIM * M3 + (size_t)gb * 64 * M3;
    const _Float16* B = Hb + (size_t)d * M3 * M3;
    f32x4 acc[4][4];
    hgemm_bt<M3, 3>(A, M3, B, M3, acc);
    int lane = threadIdx.x & 63, w = threadIdx.x >> 6;
    int qd = lane >> 4, l15 = lane & 15;
    float ide[4];
#pragma unroll
    for (int fn = 0; fn < 4; fn++)
        ide[fn] = 1.f / degE[d * M3 + w * 64 + fn * 16 + l15];
    _Float16* out = ET + (size_t)d * GDIM * M3;
#pragma unroll
    for (int fm = 0; fm < 4; fm++)
#pragma unroll
        for (int rg = 0; rg < 4; rg++) {
            int g = gb * 64 + fm * 16 + qd * 4 + rg;
#pragma unroll
            for (int fn = 0; fn < 4; fn++) {
                int e = w * 64 + fn * 16 + l15;
                out[(size_t)g * M3 + e] = (_Float16)(acc[fm][fn][rg] * ide[fn]);
            }
        }
}

// ---- K5: Y = (H^T @ E) / deg_v = HbT @ ET(B^T).  Y[d][n][g] fp16 ----
__global__ void k5_Y(const _Float16* __restrict__ HbT, const _Float16* __restrict__ ET,
                     const float* __restrict__ degV, _Float16* __restrict__ Y) {
    int nb = blockIdx.x, d = blockIdx.y;
    const _Float16* A = HbT + (size_t)d * M3 * M3 + (size_t)nb * 64 * M3;
    const _Float16* B = ET + (size_t)d * GDIM * M3;
    f32x4 acc[4][4];
    hgemm_bt<M3, 4>(A, M3, B, M3, acc);
    int lane = threadIdx.x & 63, w = threadIdx.x >> 6;
    int qd = lane >> 4, l15 = lane & 15;
    _Float16* out = Y + ((size_t)d * M3 + nb * 64) * GDIM;
#pragma unroll
    for (int fm = 0; fm < 4; fm++)
#pragma unroll
        for (int rg = 0; rg < 4; rg++) {
            int ml = fm * 16 + qd * 4 + rg;
            float idv = 1.f / degV[d * M3 + nb * 64 + ml];
#pragma unroll
            for (int fn = 0; fn < 4; fn++) {
                int g = w * 64 + fn * 16 + l15;
                out[(size_t)ml * GDIM + g] = (_Float16)(acc[fm][fn][rg] * idv);
            }
        }
}

// ---- K6: out = relu(Y @ Wh + bh) -> fp32 d_out scattered [tn|an|vn] ----
__global__ void k6_out(const _Float16* __restrict__ Y, const _Float16* __restrict__ WhT,
                       const float* __restrict__ bh, float* __restrict__ outp) {
    int b = blockIdx.x;
    const _Float16* A = Y + (size_t)b * 64 * GDIM;
    f32x4 acc[4][4];
    hgemm_bt<GDIM, 4>(A, GDIM, WhT, GDIM, acc);
    int lane = threadIdx.x & 63, w = threadIdx.x >> 6;
    int qd = lane >> 4, l15 = lane & 15;
    float bb[4];
#pragma unroll
    for (int fn = 0; fn < 4; fn++)
        bb[fn] = bh[w * 64 + fn * 16 + l15];
#pragma unroll
    for (int fm = 0; fm < 4; fm++)
#pragma unroll
        for (int rg = 0; rg < 4; rg++) {
            int r = b * 64 + fm * 16 + qd * 4 + rg;
            int d = r / M3, n = r % M3;
            int mod = n >> 6, i = n & 63;
            float* orow = outp + (size_t)(d * 64 + i) * 768 + mod * GDIM;
#pragma unroll
            for (int fn = 0; fn < 4; fn++) {
                int go = w * 64 + fn * 16 + l15;
                orow[go] = fmaxf(acc[fm][fn][rg] + bb[fn], 0.f);
            }
        }
}

// ---- K7: normalize rows, write bf16 xnb[3][4096][256] ----
__global__ void k7_norm(const float* __restrict__ outp, ushort* __restrict__ xnb) {
    int lane = threadIdx.x & 63, wv = threadIdx.x >> 6;
    int idx = blockIdx.x * 4 + wv;               // 0..12287
    int p = idx / NROW, r = idx % NROW;
    const float4* src = (const float4*)(outp + (size_t)r * 768 + p * GDIM);
    float4 x = src[lane];
    float s = x.x * x.x + x.y * x.y + x.z * x.z + x.w * x.w;
#pragma unroll
    for (int o = 1; o < 64; o <<= 1) s += __shfl_xor(s, o);
    float inv = 1.f / (sqrtf(s) + 1e-8f);
    ushort4 u;
    u.x = f2bf(x.x * inv);
    u.y = f2bf(x.y * inv);
    u.z = f2bf(x.z * inv);
    u.w = f2bf(x.w * inv);
    *(ushort4*)&xnb[((size_t)p * NROW + r) * GDIM + lane * 4] = u;
}

// ---- K8: zero rs/cs accumulators + degV ----
__global__ void k8_zero(float* __restrict__ rs, float* __restrict__ cs,
                        float* __restrict__ degV) {
    int i = blockIdx.x * 256 + threadIdx.x;
    if (i < 3 * NROW) { rs[i] = 0.f; cs[i] = 0.f; degV[i] = 0.f; }
}

// ---- K9: bf16 MFMA sim tiles; exp row/col sums + diagonal ----
#define TILE 128
#define LDK  40
__global__ __launch_bounds__(256) void k9_mfma(const ushort* __restrict__ xnb,
                                               float* __restrict__ rs,
                                               float* __restrict__ cs,
                                               float* __restrict__ diag) {
    int cj = blockIdx.x, ci = blockIdx.y, p = blockIdx.z;
    int px = (p == 2) ? 1 : 0;
    int py = (p == 0) ? 1 : 2;
    const ushort* A = xnb + ((size_t)px * NROW + ci * TILE) * GDIM;
    const ushort* B = xnb + ((size_t)py * NROW + cj * TILE) * GDIM;

    __shared__ __align__(16) ushort As[TILE * LDK];
    __shared__ __align__(16) ushort Bs[TILE * LDK];

    const int tid = threadIdx.x;
    const int lane = tid & 63, w = tid >> 6;
    const int wrow = w >> 1, wcol = w & 1;
    const int qd = lane >> 4, l15 = lane & 15;

    f32x4 acc[4][4] = {};

    for (int k0 = 0; k0 < GDIM; k0 += 32) {
#pragma unroll
        for (int i = 0; i < 2; i++) {
            int f = tid + i * 256;
            int row = f >> 2, c8 = f & 3;
            *(float4*)&As[row * LDK + c8 * 8] =
                *(const float4*)&A[(size_t)row * GDIM + k0 + c8 * 8];
            *(float4*)&Bs[row * LDK + c8 * 8] =
                *(const float4*)&B[(size_t)row * GDIM + k0 + c8 * 8];
        }
        __syncthreads();

        bf16x8 af[4], bfv[4];
#pragma unroll
        for (int fm = 0; fm < 4; fm++)
            af[fm] = *(const bf16x8*)&As[(wrow * 64 + fm * 16 + l15) * LDK + qd * 8];
#pragma unroll
        for (int fn = 0; fn < 4; fn++)
            bfv[fn] = *(const bf16x8*)&Bs[(wcol * 64 + fn * 16 + l15) * LDK + qd * 8];
#pragma unroll
        for (int fm = 0; fm < 4; fm++)
#pragma unroll
            for (int fn = 0; fn < 4; fn++)
                acc[fm][fn] = __builtin_amdgcn_mfma_f32_16x16x32_bf16(
                    af[fm], bfv[fn], acc[fm][fn], 0, 0, 0);
        __syncthreads();
    }

    float rloc[4][4] = {};
    float cloc[4] = {};
#pragma unroll
    for (int fm = 0; fm < 4; fm++)
#pragma unroll
        for (int fn = 0; fn < 4; fn++)
#pragma unroll
            for (int rg = 0; rg < 4; rg++) {
                float s = acc[fm][fn][rg] * INV_TAU;
                float e = __expf(s);
                rloc[fm][rg] += e;
                cloc[fn] += e;
                if (ci == cj && wrow == wcol && fm == fn && (qd * 4 + rg) == l15)
                    diag[p * NROW + ci * TILE + wrow * 64 + fm * 16 + qd * 4 + rg] = s;
            }
#pragma unroll
    for (int fm = 0; fm < 4; fm++)
#pragma unroll
        for (int rg = 0; rg < 4; rg++) {
            float s = rloc[fm][rg];
            s += __shfl_xor(s, 1);
            s += __shfl_xor(s, 2);
            s += __shfl_xor(s, 4);
            s += __shfl_xor(s, 8);
            if (l15 == 0)
                atomicAdd(&rs[p * NROW + ci * TILE + wrow * 64 + fm * 16 + qd * 4 + rg], s);
        }
#pragma unroll
    for (int fn = 0; fn < 4; fn++) {
        float s = cloc[fn];
        s += __shfl_xor(s, 16);
        s += __shfl_xor(s, 32);
        if (qd == 0)
            atomicAdd(&cs[p * NROW + cj * TILE + wcol * 64 + fn * 16 + l15], s);
    }
}

// ---- K10: final loss reduction ----
__global__ void k10_loss(const float* __restrict__ diag, const float* __restrict__ rs,
                         const float* __restrict__ cs, float* __restrict__ outp) {
    float acc = 0.f;
    for (int i = threadIdx.x; i < 3 * NROW; i += 256)
        acc += 2.f * diag[i] - logf(rs[i]) - logf(cs[i]);
    int lane = threadIdx.x & 63, wv = threadIdx.x >> 6;
    for (int o = 32; o; o >>= 1) acc += __shfl_down(acc, o);
    __shared__ float red[4];
    if (lane == 0) red[wv] = acc;
    __syncthreads();
    if (threadIdx.x == 0) {
        float tot = red[0] + red[1] + red[2] + red[3];
        outp[(size_t)NROW * 768] = -tot / (NROW * 6.0f);
    }
}

extern "C" void kernel_launch(void* const* d_in, const int* in_sizes, int n_in,
                              void* d_out, int out_size, void* d_ws, size_t ws_size,
                              hipStream_t stream) {
    const float* t   = (const float*)d_in[0];
    const float* a   = (const float*)d_in[1];
    const float* v   = (const float*)d_in[2];
    const float* Wfc = (const float*)d_in[3];
    const float* bfc = (const float*)d_in[4];
    const float* Wh  = (const float*)d_in[5];
    const float* bh  = (const float*)d_in[6];
    float* outp = (float*)d_out;
    float* ws = (float*)d_ws;

    // workspace layout (floats); all offsets 16B-aligned
    float* sq    = ws;                       // 12288
    float* d2    = sq + 12288;               // 2359296 (dead after k2 -> xnb)
    float* HbF   = d2 + 2359296;             // 1179648 (fp16 Hb 12288x192)
    float* HbTF  = HbF + 1179648;            // 1179648
    float* degE  = HbTF + 1179648;           // 12288
    float* degV  = degE + 12288;             // 12288
    float* featF = degV + 12288;             // 3145728 (fp16 featb 64x192x512)
    float* WfcTF = featF + 3145728;          // 65536   (fp16 256x512)
    float* WhTF  = WfcTF + 65536;            // 32768   (fp16 256x256)
    float* XTF   = WhTF + 32768;             // 1572864 (fp16 64x256x192)
    float* ETF   = XTF + 1572864;            // 1572864
    float* YF    = ETF + 1572864;            // 1572864 (fp16 12288x256)
    float* rs    = YF + 1572864;             // 12288
    float* cs    = rs + 12288;               // 12288
    float* diag  = cs + 12288;               // 12288

    _Float16* Hb    = (_Float16*)HbF;
    _Float16* HbT   = (_Float16*)HbTF;
    _Float16* featb = (_Float16*)featF;
    _Float16* WfcT  = (_Float16*)WfcTF;
    _Float16* WhT   = (_Float16*)WhTF;
    _Float16* XT    = (_Float16*)XTF;
    _Float16* ET    = (_Float16*)ETF;
    _Float16* Y     = (_Float16*)YF;
    ushort*   xnb   = (ushort*)d2;           // bf16[3][4096][256]

    kcvt   <<<6336, 256, 0, stream>>>(t, a, v, Wfc, Wh, featb, WfcT, WhT);
    k0_sq  <<<3072, 256, 0, stream>>>(t, a, v, sq);
    k1_d2  <<<dim3(6, 64), 256, 0, stream>>>(t, a, v, sq, d2);
    k8_zero<<<48, 256, 0, stream>>>(rs, cs, degV);
    k2_topk<<<3072, 256, 0, stream>>>(d2, Hb, degE, degV);
    kT_tr  <<<64, 256, 0, stream>>>(Hb, HbT);
    k3_x   <<<dim3(4, 64), 192, 0, stream>>>(WfcT, featb, bfc, XT);
    k4_E   <<<dim3(4, 64), 192, 0, stream>>>(XT, Hb, degE, ET);
    k5_Y   <<<dim3(3, 64), 256, 0, stream>>>(HbT, ET, degV, Y);
    k6_out <<<192, 256, 0, stream>>>(Y, WhT, bh, outp);
    k7_norm<<<3072, 256, 0, stream>>>(outp, xnb);
    k9_mfma<<<dim3(32, 32, 3), 256, 0, stream>>>(xnb, rs, cs, diag);
    k10_loss<<<1, 256, 0, stream>>>(diag, rs, cs, outp);
}